// Round 9
// baseline (1435.450 us; speedup 1.0000x reference)
//
#include <hip/hip_runtime.h>

// ---------- types ----------
typedef short short8 __attribute__((ext_vector_type(8)));   // 8 bf16 as i16
typedef float f32x4 __attribute__((ext_vector_type(4)));

#define GLOBAL_AS __attribute__((address_space(1)))
#define LDS_AS    __attribute__((address_space(3)))

__device__ __forceinline__ unsigned short f2bf(float f) {
    unsigned u = __builtin_bit_cast(unsigned, f);
    u += 0x7fffu + ((u >> 16) & 1u);          // round-to-nearest-even
    return (unsigned short)(u >> 16);
}

// ---------- convert kernels (memory-bound, vectorized) ----------
__global__ __launch_bounds__(256) void k_idx2bf(const int* __restrict__ idx,
                                                const float* __restrict__ cb,
                                                ushort* __restrict__ out, int n4) {
    int i = blockIdx.x * 256 + threadIdx.x;
    if (i >= n4) return;
    int4 v = reinterpret_cast<const int4*>(idx)[i];
    ushort4 o;
    o.x = f2bf(cb[v.x]); o.y = f2bf(cb[v.y]);
    o.z = f2bf(cb[v.z]); o.w = f2bf(cb[v.w]);
    reinterpret_cast<ushort4*>(out)[i] = o;
}

__global__ __launch_bounds__(256) void k_f2bf(const float* __restrict__ in,
                                              ushort* __restrict__ out, int n4) {
    int i = blockIdx.x * 256 + threadIdx.x;
    if (i >= n4) return;
    float4 v = reinterpret_cast<const float4*>(in)[i];
    ushort4 o;
    o.x = f2bf(v.x); o.y = f2bf(v.y); o.z = f2bf(v.z); o.w = f2bf(v.w);
    reinterpret_cast<ushort4*>(out)[i] = o;
}

// ---------- 256x256 read-ahead pipelined bf16 gemm_bt (round-7 schedule,
// register-dieted): C = A[M,K]*B[N,K]^T ----------
// 512 thr = 8 waves (2M x 4N), per-wave 128x64, BK=64, 2 K-tile LDS dbuf.
// Phase p issues ds_reads for phase p+1's MFMA; after barrier, counted
// lgkmcnt(N) drains exactly p's operands, leaving p+1's in flight -> LDS
// service overlaps prior MFMA cluster + barrier wait instead of serializing.
// Reads/tile: ph1=B1[4] ph2=A1[8] ph3=0 ph4=A0,B0(next tile)[12].
// lgkm waits: 4 / 8 / 0 / 12. Stages: ph1 AL(t+1)->other buf; ph2 AE(t+2),
// ph3 BE(t+2), ph4 BL(t+2) -> current buf. vmcnt(8) at ends of ph1/ph3/ph4
// (same fence layout as round 7, which PASSED refcheck; round 7's only
// failure was register spill). Register diet vs round 7:
//  - static ds_read addressing: 4 precomputed XOR-folded offsets
//    (ak0/ak1/bk0/bk1); all reads = shared-base + compile-time imm (<64KB).
//  - staging bases gAl/gBl fold srow8*4096+scol once.
// Ledger: acc 128 + operands 96 + offsets 4 + bases ~8 = ~236 <= 256.
// Swizzle (0 conflicts, r3-verified): linear LDS dest + pre-swizzled global
// col (slot s of row r holds s^(r&7)) + XOR'd read offset.

#define CH_AE(j) ((((j) & 8) << 1) | ((j) & 7))
#define CH_AL(j) (CH_AE(j) + 8)
#define CH_BE(j) ((((j) & 12) << 1) | ((j) & 3))
#define CH_BL(j) (CH_BE(j) + 4)

#define STAGE2(GB, LW, KB, CF) do {                                             \
    const int c0_ = CF(2 * w);                                                  \
    const int c1_ = CF(2 * w + 1);                                              \
    __builtin_amdgcn_global_load_lds(                                           \
        (const GLOBAL_AS void*)((GB) + (size_t)c0_ * 32768 + (KB)),             \
        (LDS_AS void*)((LW) + c0_ * 512), 16, 0, 0);                            \
    __builtin_amdgcn_global_load_lds(                                           \
        (const GLOBAL_AS void*)((GB) + (size_t)c1_ * 32768 + (KB)),             \
        (LDS_AS void*)((LW) + c1_ * 512), 16, 0, 0);                            \
} while (0)

// static-offset fragment reads: BUF/MH/NH are literal tokens
#define READ_A(DST, BUF, MH) do {                                               \
    _Pragma("unroll")                                                           \
    for (int mi = 0; mi < 4; ++mi)                                              \
        DST[0][mi] = *reinterpret_cast<const short8*>(                          \
            sAc + ak0 + ((BUF) * 32768 + (MH) * 8192 + mi * 2048));             \
    _Pragma("unroll")                                                           \
    for (int mi = 0; mi < 4; ++mi)                                              \
        DST[1][mi] = *reinterpret_cast<const short8*>(                          \
            sAc + ak1 + ((BUF) * 32768 + (MH) * 8192 + mi * 2048));             \
} while (0)

#define READ_B(DST, BUF, NH) do {                                               \
    _Pragma("unroll")                                                           \
    for (int ni = 0; ni < 2; ++ni)                                              \
        DST[0][ni] = *reinterpret_cast<const short8*>(                          \
            sBc + bk0 + ((BUF) * 32768 + (NH) * 4096 + ni * 2048));             \
    _Pragma("unroll")                                                           \
    for (int ni = 0; ni < 2; ++ni)                                              \
        DST[1][ni] = *reinterpret_cast<const short8*>(                          \
            sBc + bk1 + ((BUF) * 32768 + (NH) * 4096 + ni * 2048));             \
} while (0)

#define MFMA16(MH, NH, AF, BF)                                                  \
    _Pragma("unroll")                                                           \
    for (int k2 = 0; k2 < 2; ++k2)                                              \
        _Pragma("unroll")                                                       \
        for (int mi = 0; mi < 4; ++mi)                                          \
            _Pragma("unroll")                                                   \
            for (int ni = 0; ni < 2; ++ni)                                      \
                acc[(MH) * 4 + mi][(NH) * 2 + ni] =                             \
                    __builtin_amdgcn_mfma_f32_16x16x32_bf16(                    \
                        AF[k2][mi], BF[k2][ni], acc[(MH) * 4 + mi][(NH) * 2 + ni], 0, 0, 0)

#define VM(N) asm volatile("s_waitcnt vmcnt(" #N ")" ::: "memory")

#define ENDBAR do {                                                             \
    asm volatile("" ::: "memory");                                              \
    __builtin_amdgcn_s_barrier();                                               \
    asm volatile("" ::: "memory");                                              \
} while (0)

#define PHTOP do {                                                              \
    asm volatile("" ::: "memory");                                              \
    __builtin_amdgcn_s_barrier();                                               \
} while (0)

#define PHMID(N) do {                                                           \
    asm volatile("s_waitcnt lgkmcnt(" #N ")" ::: "memory");                     \
    __builtin_amdgcn_sched_barrier(0);                                          \
    __builtin_amdgcn_s_setprio(1);                                              \
} while (0)

// phase macros: reads-for-NEXT-phase + stage (__VA_ARGS__), barrier,
// counted lgkm, MFMA for THIS phase (operands read last phase)
#define PH1Q(BUF, ...) do { READ_B(b1f, BUF, 1); __VA_ARGS__;                   \
    PHTOP; PHMID(4);  MFMA16(0, 0, a0f, b0f);                                   \
    __builtin_amdgcn_s_setprio(0); } while (0)

#define PH2Q(BUF, ...) do { READ_A(a1f, BUF, 1); __VA_ARGS__;                   \
    PHTOP; PHMID(8);  MFMA16(0, 1, a0f, b1f);                                   \
    __builtin_amdgcn_s_setprio(0); } while (0)

#define PH3Q(...) do { __VA_ARGS__;                                             \
    PHTOP; PHMID(0);  MFMA16(1, 0, a1f, b0f);                                   \
    __builtin_amdgcn_s_setprio(0); } while (0)

#define PH4Q(NBUF, ...) do { READ_A(a0f, NBUF, 0); READ_B(b0f, NBUF, 0);        \
    __VA_ARGS__;                                                                \
    PHTOP; PHMID(12); MFMA16(1, 1, a1f, b1f);                                   \
    __builtin_amdgcn_s_setprio(0); } while (0)

#define PH4QE(...) do { __VA_ARGS__;                                            \
    PHTOP; PHMID(0);  MFMA16(1, 1, a1f, b1f);                                   \
    __builtin_amdgcn_s_setprio(0); } while (0)

// EPI=0: C=bf16, val = acc * extra[row]; EPI=1: C=f32, val = acc + extra[col]
template <int EPI>
__global__ __launch_bounds__(512, 2) void gemm256(const ushort* __restrict__ A,
                                                  const ushort* __restrict__ B,
                                                  void* __restrict__ C,
                                                  const float* __restrict__ extra) {
    constexpr int K = 4096, N = 4096;
    __shared__ ushort sA[2][256 * 64];
    __shared__ ushort sB[2][256 * 64];

    const int tid  = threadIdx.x;
    const int w    = tid >> 6;
    const int lane = tid & 63;
    const int wm = w >> 2, wn = w & 3;

    // XCD-aware swizzle (nwg % 8 == 0 for both grids)
    const int nwg = gridDim.x;
    const int sw  = ((int)blockIdx.x & 7) * (nwg >> 3) + ((int)blockIdx.x >> 3);
    const int m0 = (sw >> 4) * 256;      // 16 tiles per N-row (N=4096)
    const int n0 = (sw & 15) * 256;

    // staging bases: lane geometry folded once (global col pre-swizzled:
    // slot (lane&7) of row (lane>>3 mod 8) holds logical slot (lane&7)^(lane>>3))
    const int srow8 = lane >> 3;
    const int scol  = (((lane & 7) ^ (lane >> 3)) * 8);   // ushorts
    const ushort* gAl = A + (size_t)m0 * K + srow8 * 4096 + scol;
    const ushort* gBl = B + (size_t)n0 * K + srow8 * 4096 + scol;

    // fragment geometry (16x16x32: row=lane&15, k=(lane>>4)*8)
    const int fr   = lane & 15;
    const int fkb  = ((lane >> 4) & 3) * 16;          // byte offset along K
    const int swb  = (fr & 7) << 4;                   // read-side slot XOR
    const int arow = wm * 128 + fr;
    const int brow = wn * 64 + fr;
    // XOR-folded static read offsets (k2 folded pre-XOR; imms don't touch b4-6)
    const char* sAc = (const char*)&sA[0][0];
    const char* sBc = (const char*)&sB[0][0];
    const int ak0 = (arow * 128 + 0  + fkb) ^ swb;
    const int ak1 = (arow * 128 + 64 + fkb) ^ swb;
    const int bk0 = (brow * 128 + 0  + fkb) ^ swb;
    const int bk1 = (brow * 128 + 64 + fkb) ^ swb;

    f32x4 acc[8][4];
#pragma unroll
    for (int i = 0; i < 8; ++i)
#pragma unroll
        for (int j = 0; j < 4; ++j) acc[i][j] = (f32x4){0.f, 0.f, 0.f, 0.f};

    short8 a0f[2][4], a1f[2][4], b0f[2][2], b1f[2][2];

    // ---- prologue: stage t0 (AE,BE,BL,AL) + t1 (AE,BE,BL) = 14 loads ----
    STAGE2(gAl, sA[0], 0, CH_AE); STAGE2(gBl, sB[0], 0, CH_BE);
    STAGE2(gBl, sB[0], 0, CH_BL); STAGE2(gAl, sA[0], 0, CH_AL);
    STAGE2(gAl, sA[1], 64, CH_AE); STAGE2(gBl, sB[1], 64, CH_BE);
    STAGE2(gBl, sB[1], 64, CH_BL);
    VM(8); ENDBAR;                                    // AE,BE,BL(0) resident
    READ_A(a0f, 0, 0); READ_B(b0f, 0, 0);             // "ph4(-1)" reads

    // ---- steady pairs: tiles 0..61 ----
    for (int pr = 0; pr < 31; ++pr) {
        const int t = 2 * pr;
        const int kb1 = (t + 1) * 64, kb2 = (t + 2) * 64, kb3 = (t + 3) * 64;
        // even tile t (cur=buf0)
        PH1Q(0, STAGE2(gAl, sA[1], kb1, CH_AL)); VM(8); ENDBAR;
        PH2Q(0, STAGE2(gAl, sA[0], kb2, CH_AE));        ENDBAR;
        PH3Q(   STAGE2(gBl, sB[0], kb2, CH_BE)); VM(8); ENDBAR;
        PH4Q(1, STAGE2(gBl, sB[0], kb2, CH_BL)); VM(8); ENDBAR;
        // odd tile t+1 (cur=buf1)
        PH1Q(1, STAGE2(gAl, sA[0], kb2, CH_AL)); VM(8); ENDBAR;
        PH2Q(1, STAGE2(gAl, sA[1], kb3, CH_AE));        ENDBAR;
        PH3Q(   STAGE2(gBl, sB[1], kb3, CH_BE)); VM(8); ENDBAR;
        PH4Q(0, STAGE2(gBl, sB[1], kb3, CH_BL)); VM(8); ENDBAR;
    }
    {   // ---- tail: tile 62 (buf0) ----
        PH1Q(0, STAGE2(gAl, sA[1], 63 * 64, CH_AL)); VM(8); ENDBAR;
        PH2Q(0, ((void)0));                                 ENDBAR;
        PH3Q(((void)0));                             VM(4); ENDBAR;
        PH4Q(1, ((void)0));                          VM(2); ENDBAR;
        // ---- tail: tile 63 (buf1) ----
        PH1Q(1, ((void)0));                          VM(0); ENDBAR;
        PH2Q(1, ((void)0));                                 ENDBAR;
        PH3Q(((void)0));                                    ENDBAR;
        PH4QE(((void)0));
    }

    // ---- epilogue: C/D layout col=lane&15, row=(lane>>4)*4+reg ----
    const int rb = m0 + wm * 128 + ((lane >> 4) * 4);
    const int cb = n0 + wn * 64 + (lane & 15);
    if (EPI == 0) {
        ushort* Cw = (ushort*)C;
#pragma unroll
        for (int mi = 0; mi < 8; ++mi) {
#pragma unroll
            for (int r = 0; r < 4; ++r) {
                const int row = rb + mi * 16 + r;
                const float s = extra[row];
#pragma unroll
                for (int ni = 0; ni < 4; ++ni)
                    Cw[(size_t)row * N + cb + ni * 16] = f2bf(acc[mi][ni][r] * s);
            }
        }
    } else {
        float* Cf = (float*)C;
#pragma unroll
        for (int ni = 0; ni < 4; ++ni) {
            const float b = extra[cb + ni * 16];
#pragma unroll
            for (int mi = 0; mi < 8; ++mi) {
#pragma unroll
                for (int r = 0; r < 4; ++r) {
                    const int row = rb + mi * 16 + r;
                    Cf[(size_t)row * N + cb + ni * 16] = acc[mi][ni][r] + b;
                }
            }
        }
    }
}

// ---------- launch ----------
extern "C" void kernel_launch(void* const* d_in, const int* in_sizes, int n_in,
                              void* d_out, int out_size, void* d_ws, size_t ws_size,
                              hipStream_t stream) {
    const float* x     = (const float*)d_in[0];   // (4,2048,4096) f32
    const int*   widx  = (const int*)  d_in[1];   // (4096,4096) i32
    const float* wscal = (const float*)d_in[2];   // (4096,)
    const float* bias  = (const float*)d_in[3];   // (4096,)
    const float* rot   = (const float*)d_in[4];   // (4096,4096) f32
    const float* cb    = (const float*)d_in[5];   // (16,)
    float* out = (float*)d_out;                   // (4,2048,4096) f32

    constexpr size_t IN_F = 4096, OUT_F = 4096, MTOK = 8192;
    char* ws = (char*)d_ws;
    ushort* wq   = (ushort*)(ws);                 // 32 MiB: codebook[idx] bf16
    ushort* rbuf = (ushort*)(ws + 33554432);      // 32 MiB: rotation bf16
    ushort* xb   = (ushort*)(ws + 67108864);      // 64 MiB: x bf16
    ushort* wb   = (ushort*)(ws + 134217728);     // 32 MiB: dequantized W bf16
    (void)ws_size; (void)in_sizes; (void)n_in; (void)out_size;

    // converts (memory-bound)
    {
        int n4 = (int)(OUT_F * IN_F / 4);
        k_idx2bf<<<n4 / 256, 256, 0, stream>>>(widx, cb, wq, n4);
        k_f2bf<<<n4 / 256, 256, 0, stream>>>(rot, rbuf, n4);
        int n4x = (int)(MTOK * IN_F / 4);
        k_f2bf<<<n4x / 256, 256, 0, stream>>>(x, xb, n4x);
    }

    // GEMM A: W[o,j] = scale[o] * sum_i Wq[o,i] R[j,i]   (M=4096 -> 256 wgs)
    gemm256<0><<<dim3(256), 512, 0, stream>>>(wq, rbuf, (void*)wb, wscal);

    // GEMM B: out[m,o] = sum_j x[m,j] W[o,j] + bias[o]   (M=8192 -> 512 wgs)
    gemm256<1><<<dim3(512), 512, 0, stream>>>(xb, wb, (void*)out, bias);
}

// Round 10
// 453.823 us; speedup vs baseline: 3.1630x; 3.1630x over previous
//
#include <hip/hip_runtime.h>

// ---------- types ----------
typedef short short8 __attribute__((ext_vector_type(8)));   // 8 bf16 as i16
typedef float f32x4 __attribute__((ext_vector_type(4)));

#define GLOBAL_AS __attribute__((address_space(1)))
#define LDS_AS    __attribute__((address_space(3)))

__device__ __forceinline__ unsigned short f2bf(float f) {
    unsigned u = __builtin_bit_cast(unsigned, f);
    u += 0x7fffu + ((u >> 16) & 1u);          // round-to-nearest-even
    return (unsigned short)(u >> 16);
}

// ---------- convert kernels (memory-bound, vectorized) ----------
__global__ __launch_bounds__(256) void k_idx2bf(const int* __restrict__ idx,
                                                const float* __restrict__ cb,
                                                ushort* __restrict__ out, int n4) {
    int i = blockIdx.x * 256 + threadIdx.x;
    if (i >= n4) return;
    int4 v = reinterpret_cast<const int4*>(idx)[i];
    ushort4 o;
    o.x = f2bf(cb[v.x]); o.y = f2bf(cb[v.y]);
    o.z = f2bf(cb[v.z]); o.w = f2bf(cb[v.w]);
    reinterpret_cast<ushort4*>(out)[i] = o;
}

__global__ __launch_bounds__(256) void k_f2bf(const float* __restrict__ in,
                                              ushort* __restrict__ out, int n4) {
    int i = blockIdx.x * 256 + threadIdx.x;
    if (i >= n4) return;
    float4 v = reinterpret_cast<const float4*>(in)[i];
    ushort4 o;
    o.x = f2bf(v.x); o.y = f2bf(v.y); o.z = f2bf(v.z); o.w = f2bf(v.w);
    reinterpret_cast<ushort4*>(out)[i] = o;
}

// ---------- 256x256 bf16 gemm_bt: round-6 schedule + static addressing ----
// 512 thr = 8 waves (2M x 4N), per-wave 128x64, BK=64, 2 K-tile LDS dbuf.
// Per K-tile 4 quadrant phases; each phase reads its OWN MFMA operands
// (12/4/8/0 ds_read_b128), stages 1 half-tile (2 gload_lds), then
// [ph1: lgkmcnt(8) throttle] -> barrier -> lgkmcnt(0) -> setprio(1) ->
// 16 MFMA -> setprio(0) -> [ph4: vmcnt(6)] -> barrier.   (= round 6, = m201)
// NEW vs round 6: all ds_read addresses are base-VGPR + compile-time imm
// (4 precomputed XOR-folded offsets ak0/ak1/bk0/bk1; imm <= 47KB < 64KB),
// and staging bases gAl/gBl fold lane geometry once -> per-phase VALU ~0
// (round 6's 18.5% VALUBusy was per-phase address recomputation delaying
// read issue and stretching every lgkm(0) drain).
// Register ledger: acc 128 (AGPR) + operands 64 (aF/b0f/b1f) + addr ~20
// = ~214 <= 256 cap at 8 waves/CU -> no spill (spill tell: WRITE_SIZE).
// Stages (tile t, cur=t&1): ph1 AL(t+1)->buf[cur^1]; ph2 AE(t+2), ph3
// BE(t+2), ph4 BL(t+2) -> buf[cur]. vm(6) at ph4 completes tile t+1 and
// leaves {AE,BE,BL}(t+2) in flight. Race-safety: every staged region's
// reads were drained by a lgkm(0) >= 1 barrier earlier (verified per
// region). Tails: tile 62 stages only AL(63), vm(0) at ph4; tile 63 none.
// Swizzle (0 conflicts, r3/r6-verified): linear LDS dest + pre-swizzled
// global col (slot s of row r holds s^(r&7)) + XOR-folded read offsets.

#define CH_AE(j) ((((j) & 8) << 1) | ((j) & 7))
#define CH_AL(j) (CH_AE(j) + 8)
#define CH_BE(j) ((((j) & 12) << 1) | ((j) & 3))
#define CH_BL(j) (CH_BE(j) + 4)

#define STAGE2(GB, LW, KB, CF) do {                                             \
    const int c0_ = CF(2 * w);                                                  \
    const int c1_ = CF(2 * w + 1);                                              \
    __builtin_amdgcn_global_load_lds(                                           \
        (const GLOBAL_AS void*)((GB) + (size_t)c0_ * 32768 + (KB)),             \
        (LDS_AS void*)((LW) + c0_ * 512), 16, 0, 0);                            \
    __builtin_amdgcn_global_load_lds(                                           \
        (const GLOBAL_AS void*)((GB) + (size_t)c1_ * 32768 + (KB)),             \
        (LDS_AS void*)((LW) + c1_ * 512), 16, 0, 0);                            \
} while (0)

// static-offset fragment reads: BUF/MH/NH are literal tokens -> ds imm
#define READ_A(DST, BUF, MH) do {                                               \
    _Pragma("unroll")                                                           \
    for (int mi = 0; mi < 4; ++mi)                                              \
        DST[0][mi] = *reinterpret_cast<const short8*>(                          \
            sAc + ak0 + ((BUF) * 32768 + (MH) * 8192 + mi * 2048));             \
    _Pragma("unroll")                                                           \
    for (int mi = 0; mi < 4; ++mi)                                              \
        DST[1][mi] = *reinterpret_cast<const short8*>(                          \
            sAc + ak1 + ((BUF) * 32768 + (MH) * 8192 + mi * 2048));             \
} while (0)

#define READ_B(DST, BUF, NH) do {                                               \
    _Pragma("unroll")                                                           \
    for (int ni = 0; ni < 2; ++ni)                                              \
        DST[0][ni] = *reinterpret_cast<const short8*>(                          \
            sBc + bk0 + ((BUF) * 32768 + (NH) * 4096 + ni * 2048));             \
    _Pragma("unroll")                                                           \
    for (int ni = 0; ni < 2; ++ni)                                              \
        DST[1][ni] = *reinterpret_cast<const short8*>(                          \
            sBc + bk1 + ((BUF) * 32768 + (NH) * 4096 + ni * 2048));             \
} while (0)

#define MFMA16(MH, NH, AF, BF)                                                  \
    _Pragma("unroll")                                                           \
    for (int k2 = 0; k2 < 2; ++k2)                                              \
        _Pragma("unroll")                                                       \
        for (int mi = 0; mi < 4; ++mi)                                          \
            _Pragma("unroll")                                                   \
            for (int ni = 0; ni < 2; ++ni)                                      \
                acc[(MH) * 4 + mi][(NH) * 2 + ni] =                             \
                    __builtin_amdgcn_mfma_f32_16x16x32_bf16(                    \
                        AF[k2][mi], BF[k2][ni], acc[(MH) * 4 + mi][(NH) * 2 + ni], 0, 0, 0)

#define PH_MID do {                                                             \
    asm volatile("" ::: "memory");                                              \
    __builtin_amdgcn_s_barrier();                                               \
    asm volatile("s_waitcnt lgkmcnt(0)" ::: "memory");                          \
    __builtin_amdgcn_sched_barrier(0);                                          \
    __builtin_amdgcn_s_setprio(1);                                              \
} while (0)

#define PH_END do {                                                             \
    __builtin_amdgcn_s_setprio(0);                                              \
    asm volatile("" ::: "memory");                                              \
    __builtin_amdgcn_s_barrier();                                               \
    asm volatile("" ::: "memory");                                              \
} while (0)

// ph1: 12 reads (A0,B0) + stage + lgkm(8) throttle (m201's 12-read rule)
#define PH1S(BUF, ...) do {                                                     \
    READ_A(aF, BUF, 0); READ_B(b0f, BUF, 0);                                    \
    __VA_ARGS__;                                                                \
    asm volatile("s_waitcnt lgkmcnt(8)" ::: "memory");                          \
    PH_MID; MFMA16(0, 0, aF, b0f); PH_END;                                      \
} while (0)

#define PH2S(BUF, ...) do {                                                     \
    READ_B(b1f, BUF, 1);                                                        \
    __VA_ARGS__;                                                                \
    PH_MID; MFMA16(0, 1, aF, b1f); PH_END;                                      \
} while (0)

#define PH3S(BUF, ...) do {                                                     \
    READ_A(aF, BUF, 1);                                                         \
    __VA_ARGS__;                                                                \
    PH_MID; MFMA16(1, 0, aF, b0f); PH_END;                                      \
} while (0)

#define PH4S(FN, ...) do {                                                      \
    __VA_ARGS__;                                                                \
    PH_MID; MFMA16(1, 1, aF, b1f);                                              \
    __builtin_amdgcn_s_setprio(0);                                              \
    asm volatile("s_waitcnt vmcnt(" #FN ")" ::: "memory");                      \
    __builtin_amdgcn_s_barrier();                                               \
    asm volatile("" ::: "memory");                                              \
} while (0)

#define PH4SNF(...) do {                                                        \
    __VA_ARGS__;                                                                \
    PH_MID; MFMA16(1, 1, aF, b1f); PH_END;                                      \
} while (0)

// EPI=0: C=bf16, val = acc * extra[row]; EPI=1: C=f32, val = acc + extra[col]
template <int EPI>
__global__ __launch_bounds__(512, 2) void gemm256(const ushort* __restrict__ A,
                                                  const ushort* __restrict__ B,
                                                  void* __restrict__ C,
                                                  const float* __restrict__ extra) {
    constexpr int K = 4096, N = 4096;
    __shared__ ushort sA[2][256 * 64];
    __shared__ ushort sB[2][256 * 64];

    const int tid  = threadIdx.x;
    const int w    = tid >> 6;
    const int lane = tid & 63;
    const int wm = w >> 2, wn = w & 3;

    // XCD-aware swizzle (nwg % 8 == 0 for both grids)
    const int nwg = gridDim.x;
    const int sw  = ((int)blockIdx.x & 7) * (nwg >> 3) + ((int)blockIdx.x >> 3);
    const int m0 = (sw >> 4) * 256;      // 16 tiles per N-row (N=4096)
    const int n0 = (sw & 15) * 256;

    // staging bases: lane geometry folded once (global col pre-swizzled:
    // slot (lane&7) of row (lane>>3 mod 8) holds logical slot (lane&7)^(lane>>3))
    const int srow8 = lane >> 3;
    const int scol  = (((lane & 7) ^ (lane >> 3)) * 8);   // ushorts
    const ushort* gAl = A + (size_t)m0 * K + srow8 * 4096 + scol;
    const ushort* gBl = B + (size_t)n0 * K + srow8 * 4096 + scol;

    // fragment geometry (16x16x32: row=lane&15, k=(lane>>4)*8)
    const int fr   = lane & 15;
    const int fkb  = ((lane >> 4) & 3) * 16;          // byte offset along K
    const int swb  = (fr & 7) << 4;                   // read-side slot XOR
    const int arow = wm * 128 + fr;
    const int brow = wn * 64 + fr;
    // XOR-folded static read offsets (k2 folded pre-XOR; imms don't touch b4-6)
    const char* sAc = (const char*)&sA[0][0];
    const char* sBc = (const char*)&sB[0][0];
    const int ak0 = (arow * 128 + 0  + fkb) ^ swb;
    const int ak1 = (arow * 128 + 64 + fkb) ^ swb;
    const int bk0 = (brow * 128 + 0  + fkb) ^ swb;
    const int bk1 = (brow * 128 + 64 + fkb) ^ swb;

    f32x4 acc[8][4];
#pragma unroll
    for (int i = 0; i < 8; ++i)
#pragma unroll
        for (int j = 0; j < 4; ++j) acc[i][j] = (f32x4){0.f, 0.f, 0.f, 0.f};

    short8 aF[2][4], b0f[2][2], b1f[2][2];

    // ---- prologue: stage t0 (AE,BE,BL,AL) + t1 (AE,BE,BL) = 14 loads ----
    STAGE2(gAl, sA[0], 0, CH_AE); STAGE2(gBl, sB[0], 0, CH_BE);
    STAGE2(gBl, sB[0], 0, CH_BL); STAGE2(gAl, sA[0], 0, CH_AL);
    STAGE2(gAl, sA[1], 64, CH_AE); STAGE2(gBl, sB[1], 64, CH_BE);
    STAGE2(gBl, sB[1], 64, CH_BL);
    asm volatile("s_waitcnt vmcnt(6)" ::: "memory");   // tile0 fully resident
    __builtin_amdgcn_s_barrier();
    asm volatile("" ::: "memory");

    // ---- steady pairs: tiles 0..61 (stage refs <= tile 63) ----
    for (int pr = 0; pr < 31; ++pr) {
        const int t = 2 * pr;
        const int kb1 = (t + 1) * 64, kb2 = (t + 2) * 64, kb3 = (t + 3) * 64;
        // even tile t (buf0)
        PH1S(0, STAGE2(gAl, sA[1], kb1, CH_AL));
        PH2S(0, STAGE2(gAl, sA[0], kb2, CH_AE));
        PH3S(0, STAGE2(gBl, sB[0], kb2, CH_BE));
        PH4S(6, STAGE2(gBl, sB[0], kb2, CH_BL));
        // odd tile t+1 (buf1)
        PH1S(1, STAGE2(gAl, sA[0], kb2, CH_AL));
        PH2S(1, STAGE2(gAl, sA[1], kb3, CH_AE));
        PH3S(1, STAGE2(gBl, sB[1], kb3, CH_BE));
        PH4S(6, STAGE2(gBl, sB[1], kb3, CH_BL));
    }
    {   // ---- tail: tile 62 (buf0): stage only AL(63); drain at ph4 ----
        PH1S(0, STAGE2(gAl, sA[1], 63 * 64, CH_AL));
        PH2S(0, ((void)0));
        PH3S(0, ((void)0));
        PH4S(0, ((void)0));
        // ---- tail: tile 63 (buf1): no staging, no fence ----
        PH1S(1, ((void)0));
        PH2S(1, ((void)0));
        PH3S(1, ((void)0));
        PH4SNF(((void)0));
    }

    // ---- epilogue: C/D layout col=lane&15, row=(lane>>4)*4+reg ----
    const int rb = m0 + wm * 128 + ((lane >> 4) * 4);
    const int cb = n0 + wn * 64 + (lane & 15);
    if (EPI == 0) {
        ushort* Cw = (ushort*)C;
#pragma unroll
        for (int mi = 0; mi < 8; ++mi) {
#pragma unroll
            for (int r = 0; r < 4; ++r) {
                const int row = rb + mi * 16 + r;
                const float s = extra[row];
#pragma unroll
                for (int ni = 0; ni < 4; ++ni)
                    Cw[(size_t)row * N + cb + ni * 16] = f2bf(acc[mi][ni][r] * s);
            }
        }
    } else {
        float* Cf = (float*)C;
#pragma unroll
        for (int ni = 0; ni < 4; ++ni) {
            const float b = extra[cb + ni * 16];
#pragma unroll
            for (int mi = 0; mi < 8; ++mi) {
#pragma unroll
                for (int r = 0; r < 4; ++r) {
                    const int row = rb + mi * 16 + r;
                    Cf[(size_t)row * N + cb + ni * 16] = acc[mi][ni][r] + b;
                }
            }
        }
    }
}

// ---------- launch ----------
extern "C" void kernel_launch(void* const* d_in, const int* in_sizes, int n_in,
                              void* d_out, int out_size, void* d_ws, size_t ws_size,
                              hipStream_t stream) {
    const float* x     = (const float*)d_in[0];   // (4,2048,4096) f32
    const int*   widx  = (const int*)  d_in[1];   // (4096,4096) i32
    const float* wscal = (const float*)d_in[2];   // (4096,)
    const float* bias  = (const float*)d_in[3];   // (4096,)
    const float* rot   = (const float*)d_in[4];   // (4096,4096) f32
    const float* cb    = (const float*)d_in[5];   // (16,)
    float* out = (float*)d_out;                   // (4,2048,4096) f32

    constexpr size_t IN_F = 4096, OUT_F = 4096, MTOK = 8192;
    char* ws = (char*)d_ws;
    ushort* wq   = (ushort*)(ws);                 // 32 MiB: codebook[idx] bf16
    ushort* rbuf = (ushort*)(ws + 33554432);      // 32 MiB: rotation bf16
    ushort* xb   = (ushort*)(ws + 67108864);      // 64 MiB: x bf16
    ushort* wb   = (ushort*)(ws + 134217728);     // 32 MiB: dequantized W bf16
    (void)ws_size; (void)in_sizes; (void)n_in; (void)out_size;

    // converts (memory-bound)
    {
        int n4 = (int)(OUT_F * IN_F / 4);
        k_idx2bf<<<n4 / 256, 256, 0, stream>>>(widx, cb, wq, n4);
        k_f2bf<<<n4 / 256, 256, 0, stream>>>(rot, rbuf, n4);
        int n4x = (int)(MTOK * IN_F / 4);
        k_f2bf<<<n4x / 256, 256, 0, stream>>>(x, xb, n4x);
    }

    // GEMM A: W[o,j] = scale[o] * sum_i Wq[o,i] R[j,i]   (M=4096 -> 256 wgs)
    gemm256<0><<<dim3(256), 512, 0, stream>>>(wq, rbuf, (void*)wb, wscal);

    // GEMM B: out[m,o] = sum_j x[m,j] W[o,j] + bias[o]   (M=8192 -> 512 wgs)
    gemm256<1><<<dim3(512), 512, 0, stream>>>(xb, wb, (void*)out, bias);
}